// Round 12
// baseline (202.910 us; speedup 1.0000x reference)
//
#include <hip/hip_runtime.h>

// CP-decomposed 3D conv (AirConv3D): B=1, Cin=32, Cout=64, 56^3, K=3, pad=1, rank=53.
// All-f32. History: R16 k3c two-phase chunked 43us (best verified k3);
// R18 k3r acc[64] 61us (TLP starvation); R19 k3p2 float2 pipeline under
// (512,4)=cap64 -> VGPR pinned 64, WRITE 131.7MB (3x) = SPILL, 98us — BUT
// 2.27TB/s + 45.8% VALUBusy proves the pipeline overlap works; true demand
// ~70-75 regs (staging 18 + acc 16 + per-lane masked weights in VGPR + addr).
// Toolchain map: (512,4)->cap 64 (32 w/CU), (512,2)->cap 128 (16 w/CU).
// R20: ONE KNOB: __launch_bounds__(512,3) -> cap ~80, 24 waves/CU.
// Go/no-go: VGPR 72-80 AND WRITE==43904 KB exactly -> dur 25-35us.
// If VGPR==64 or WRITE>50MB: pipeline needs >80 regs, revert to k3c for good.
// k1d: R19 batched phases (14 dots full-unroll -> 28 independent shfls ->
// blend+store), quarters r0=13*ry. Unverified in profile; should surface now.
// NOTE: one ~43us fillBuffer (268MB ws re-poison) sits in the timed window.
// Pipeline: k0_t -> k1d -> k3p2. Fallback (small ws): R5 pipeline (known good).

#define NP 175616   // 56*56*56
#define NP2 87808   // NP/2 float2 columns
#define HSTR 3136   // 56*56
#define H2 1568     // HSTR/2 float2 per h-plane
#define W2 28       // 56/2 float2 per w-row
#define CIN 32
#define RK 53
#define COUT 64
#define SCR 53      // fallback scratch slice base in d_out

// ---- k0: Ut[r*32+c] = Ucin[c*53+r] ----
__global__ __launch_bounds__(256) void k0_t(const float* __restrict__ Ucin,
                                            float* __restrict__ Ut)
{
    int t = blockIdx.x * 256 + threadIdx.x;
    if (t < RK * CIN) {
        int r = t >> 5, c = t & 31;
        Ut[t] = Ucin[c * RK + r];
    }
}

// ---- k1d: T1d[r,p] = d-conv(sum_c x[c,p]*Ut[r][c]), batched ILP ----
// Block = 4 waves; wave = one (h,w) row (lanes 0..55 = d). blockIdx.y = rank
// quarter (14 ranks, overlapping by 1: duplicates write identical data).
__global__ __launch_bounds__(256) void k1d(
    const float* __restrict__ x, const float* __restrict__ Ut,
    const float* __restrict__ Ukd, float* __restrict__ T1d)
{
    const int lane = threadIdx.x & 63;          // d index
    const int row  = blockIdx.x * 4 + (threadIdx.x >> 6);   // (h,w) row in [0,3136)
    const int p    = row * 56 + lane;
    const bool act = (lane < 56);
    const int pc   = act ? p : (p - 8);         // clamp: lanes 56..63 in-bounds

    float xv[CIN];
#pragma unroll
    for (int c = 0; c < CIN; ++c) xv[c] = x[c * NP + pc];
#pragma unroll
    for (int c = 0; c < CIN; ++c) asm volatile("" : "+v"(xv[c]));  // pin in VGPRs

    const int r0 = blockIdx.y * 13;             // [0,14) [13,27) [26,40) [39,53)

    // phase A: all 14 dots (independent 4-partial chains, full unroll)
    float acc[14];
#pragma unroll
    for (int rr = 0; rr < 14; ++rr) {
        const float* U = Ut + (r0 + rr) * CIN;  // uniform -> s_load
        float a0 = 0.f, a1 = 0.f, a2 = 0.f, a3 = 0.f;
#pragma unroll
        for (int c = 0; c < CIN; c += 4) {
            a0 += xv[c]     * U[c];
            a1 += xv[c + 1] * U[c + 1];
            a2 += xv[c + 2] * U[c + 2];
            a3 += xv[c + 3] * U[c + 3];
        }
        acc[rr] = (a0 + a1) + (a2 + a3);
    }

    // phase B: all shfls issued back-to-back (independent -> DS pipelines)
    float lm[14], rp[14];
#pragma unroll
    for (int rr = 0; rr < 14; ++rr) {
        lm[rr] = __shfl_up(acc[rr], 1, 64);
        rp[rr] = __shfl_down(acc[rr], 1, 64);
    }

    // phase C: blend + store
#pragma unroll
    for (int rr = 0; rr < 14; ++rr) {
        const int r = r0 + rr;
        float l  = (lane == 0)  ? 0.f : lm[rr];
        float rv = (lane == 55) ? 0.f : rp[rr];
        float res = l * Ukd[r] + acc[rr] * Ukd[RK + r] + rv * Ukd[2 * RK + r];
        if (act) T1d[(size_t)r * NP + p] = res;
    }
}

// ---- k3p2: pipelined double-buffer w+h conv + 53->64 proj + bias, float2 ----
// Wave wv stages rank g*8+wv (9 loads issued EARLY); all waves project the
// previous group's 8 ranks from LDS while those loads fly; 1 barrier/group.
// (512,3) => VGPR cap ~80 (toolchain: 2nd arg ~ min blocks/CU), 24 waves/CU.
// True demand ~70-75 (R19 measured spill at cap 64).
__global__ __launch_bounds__(512, 3) void k3p2(
    const float2* __restrict__ Ta, const float* __restrict__ Ucout,
    const float* __restrict__ bias, const float* __restrict__ Ukh,
    const float* __restrict__ Ukw, float2* __restrict__ Out)
{
    __shared__ float2 tld[2][8][64];             // 8 KB double buffer

    const int lane = threadIdx.x & 63;
    const int wv   = threadIdx.x >> 6;           // 0..7

    // bijective XCD swizzle (m204); nwg = 1372
    const int nwg = gridDim.x;
    const int qx = nwg >> 3, rx = nwg & 7;
    const int xcd = blockIdx.x & 7, loc = blockIdx.x >> 3;
    const int swz = ((xcd < rx) ? xcd * (qx + 1) : rx * (qx + 1) + (xcd - rx) * qx) + loc;

    const int q  = swz * 64 + lane;              // float2 column in [0,NP2)
    const int h  = q / H2;
    const int rm = q - h * H2;
    const int w  = rm / W2;
    const int om = (h > 0)  ? -H2 : 0;
    const int op = (h < 55) ?  H2 : 0;
    const int oa = (w > 0)  ? -W2 : 0;
    const int oc = (w < 55) ?  W2 : 0;
    const float mh0 = (h > 0)  ? 1.f : 0.f;
    const float mh2 = (h < 55) ? 1.f : 0.f;
    const float mw0 = (w > 0)  ? 1.f : 0.f;
    const float mw2 = (w < 55) ? 1.f : 0.f;

    const float2* Sq = Ta + q;
    const int og = __builtin_amdgcn_readfirstlane(wv << 3);  // 0,8,...,56

    float2 a[8];
#pragma unroll
    for (int o = 0; o < 8; ++o) {
        float b = bias[og + o];
        a[o].x = b; a[o].y = b;
    }

#define LOAD9(S) \
    v00 = (S)[om + oa]; v01 = (S)[om]; v02 = (S)[om + oc]; \
    v10 = (S)[oa];      v11 = (S)[0];  v12 = (S)[oc];      \
    v20 = (S)[op + oa]; v21 = (S)[op]; v22 = (S)[op + oc];

#define WHBLEND(t, r) { \
    const float kw0 = mw0 * Ukw[r]; \
    const float kw1 = Ukw[RK + (r)]; \
    const float kw2 = mw2 * Ukw[2 * RK + (r)]; \
    const float kh0 = mh0 * Ukh[r]; \
    const float kh1 = Ukh[RK + (r)]; \
    const float kh2 = mh2 * Ukh[2 * RK + (r)]; \
    t.x = (v00.x * kw0 + v01.x * kw1 + v02.x * kw2) * kh0 \
        + (v10.x * kw0 + v11.x * kw1 + v12.x * kw2) * kh1 \
        + (v20.x * kw0 + v21.x * kw1 + v22.x * kw2) * kh2; \
    t.y = (v00.y * kw0 + v01.y * kw1 + v02.y * kw2) * kh0 \
        + (v10.y * kw0 + v11.y * kw1 + v12.y * kw2) * kh1 \
        + (v20.y * kw0 + v21.y * kw1 + v22.y * kw2) * kh2; }

    float2 v00, v01, v02, v10, v11, v12, v20, v21, v22;

    // prologue: stage group 0 (rank = wv)
    {
        const float2* S = Sq + (size_t)wv * NP2;
        LOAD9(S);
        float2 t;
        WHBLEND(t, wv);
        tld[0][wv][lane] = t;
    }
    __syncthreads();

#pragma unroll
    for (int g = 0; g < 7; ++g) {
        const int rn = (g + 1) * 8 + wv;             // rank to stage next
        const bool hn = (g < 6) && (rn < RK);        // wave-uniform guard
        if (hn) {
            const float2* S = Sq + (size_t)rn * NP2;
            LOAD9(S);                                // issue early; used after proj
        }
        // project group g from LDS (under the in-flight loads)
        const int n = (g == 6) ? 5 : 8;
#pragma unroll
        for (int rr = 0; rr < 8; ++rr) {
            if (rr < n) {
                float2 t = tld[g & 1][rr][lane];
                const float* Ur = Ucout + (g * 8 + rr) * COUT + og;  // s_load
#pragma unroll
                for (int o = 0; o < 8; ++o) {
                    float u = Ur[o];
                    a[o].x += t.x * u; a[o].y += t.y * u;
                }
            }
        }
        if (hn) {
            float2 t;
            WHBLEND(t, rn);                          // vmcnt wait lands here
            tld[(g + 1) & 1][wv][lane] = t;
        }
        if (g < 6) __syncthreads();
    }

#pragma unroll
    for (int o = 0; o < 8; ++o)
        Out[(size_t)(og + o) * NP2 + q] = a[o];
#undef LOAD9
#undef WHBLEND
}

// ===================== fallback path (R5, known good) =====================

__global__ __launch_bounds__(256) void k1_chunk(
    const float* __restrict__ x, const float* __restrict__ Ucin,
    float* T, int r0, int nr)
{
    __shared__ float sU[11 * CIN];
    const int tid = threadIdx.x;
    for (int t = tid; t < nr * CIN; t += 256) {
        int lr = t >> 5, c = t & 31;
        sU[t] = Ucin[c * RK + (r0 + lr)];
    }
    __syncthreads();
    const int p = blockIdx.x * 256 + tid;
    float xv[CIN];
#pragma unroll
    for (int c = 0; c < CIN; ++c) xv[c] = x[c * NP + p];
#pragma unroll 1
    for (int lr = 0; lr < nr; ++lr) {
        float acc = 0.f;
#pragma unroll
        for (int c = 0; c < CIN; ++c) acc += xv[c] * sU[lr * CIN + c];
        T[(size_t)(SCR + lr) * NP + p] = acc;
    }
}

__global__ __launch_bounds__(256) void k2_chunk(
    const float* __restrict__ Ukh, const float* __restrict__ Ukw,
    const float* __restrict__ Ukd, float* T, int r0)
{
    __shared__ float sIn[5800];
    __shared__ float sA[5600];
    const int lr = blockIdx.z;
    const int r  = r0 + lr;
    const int h0 = blockIdx.x * 8, w0 = blockIdx.y * 8;
    const int tid = threadIdx.x;
    const float kh0 = Ukh[r], kh1 = Ukh[RK + r], kh2 = Ukh[2 * RK + r];
    const float kw0 = Ukw[r], kw1 = Ukw[RK + r], kw2 = Ukw[2 * RK + r];
    const float kd0 = Ukd[r], kd1 = Ukd[RK + r], kd2 = Ukd[2 * RK + r];
    const float* T1r = T + (size_t)(SCR + lr) * NP;

    for (int idx = tid; idx < 5800; idx += 256) {
        int d = idx % 58; int t2 = idx / 58; int ww = t2 % 10; int hh = t2 / 10;
        int gh = h0 + hh - 1, gw = w0 + ww - 1, gd = d - 1;
        float v = 0.f;
        if ((unsigned)gh < 56u && (unsigned)gw < 56u && (unsigned)gd < 56u)
            v = T1r[gh * HSTR + gw * 56 + gd];
        sIn[idx] = v;
    }
    __syncthreads();
    for (int idx = tid; idx < 5600; idx += 256) {
        int d = idx % 56; int t2 = idx / 56; int ww = t2 % 10; int hh = t2 / 10;
        const float* b = &sIn[(hh * 10 + ww) * 58 + d];
        sA[idx] = b[0] * kd0 + b[1] * kd1 + b[2] * kd2;
    }
    __syncthreads();
    const float k00 = kh0 * kw0, k01 = kh0 * kw1, k02 = kh0 * kw2;
    const float k10 = kh1 * kw0, k11 = kh1 * kw1, k12 = kh1 * kw2;
    const float k20 = kh2 * kw0, k21 = kh2 * kw1, k22 = kh2 * kw2;
    for (int idx = tid; idx < 3584; idx += 256) {
        int d = idx % 56; int t2 = idx / 56; int ww = t2 % 8; int hh = t2 / 8;
        const float* a = &sA[(hh * 10 + ww) * 56 + d];
        float acc = a[0]    * k00 + a[56]   * k01 + a[112]  * k02
                  + a[560]  * k10 + a[616]  * k11 + a[672]  * k12
                  + a[1120] * k20 + a[1176] * k21 + a[1232] * k22;
        T[(size_t)r * NP + (h0 + hh) * HSTR + (w0 + ww) * 56 + d] = acc;
    }
}

__global__ __launch_bounds__(256) void k3_out(
    float* T, const float* __restrict__ Ucout, const float* __restrict__ bias)
{
    __shared__ float sUo[RK * COUT];
    __shared__ float sB[COUT];
    const int tid = threadIdx.x;
    for (int t = tid; t < RK * COUT; t += 256) sUo[t] = Ucout[t];
    if (tid < COUT) sB[tid] = bias[tid];
    __syncthreads();
    const int p = blockIdx.x * 256 + tid;
    float acc[COUT];
#pragma unroll
    for (int o = 0; o < COUT; ++o) acc[o] = sB[o];
#pragma unroll 1
    for (int r = 0; r < RK; ++r) {
        float t = T[(size_t)r * NP + p];
        const float* Ur = &sUo[r * COUT];
#pragma unroll
        for (int o = 0; o < COUT; ++o) acc[o] += t * Ur[o];
    }
#pragma unroll
    for (int o = 0; o < COUT; ++o) T[(size_t)o * NP + p] = acc[o];
}

// ===================== launch =====================

extern "C" void kernel_launch(void* const* d_in, const int* in_sizes, int n_in,
                              void* d_out, int out_size, void* d_ws, size_t ws_size,
                              hipStream_t stream)
{
    const float* x     = (const float*)d_in[0];
    const float* Ukh   = (const float*)d_in[1];
    const float* Ukw   = (const float*)d_in[2];
    const float* Ukd   = (const float*)d_in[3];
    const float* Ucin  = (const float*)d_in[4];
    const float* Ucout = (const float*)d_in[5];
    const float* bias  = (const float*)d_in[6];

    const size_t t1_bytes = (size_t)RK * NP * sizeof(float);   // 37.2 MB

    if (ws_size >= t1_bytes + 8192) {
        float* T1 = (float*)d_ws;
        float* Ut = (float*)((char*)d_ws + t1_bytes);          // 6.8 KB
        k0_t<<<7, 256, 0, stream>>>(Ucin, Ut);
        k1d<<<dim3(HSTR / 4, 4), 256, 0, stream>>>(x, Ut, Ukd, T1);  // 3136 blocks
        k3p2<<<NP2 / 64, 512, 0, stream>>>((const float2*)T1, Ucout, bias, Ukh,
                                           Ukw, (float2*)d_out);     // 1372 blocks
    } else {
        float* T = (float*)d_out;
        for (int r0 = 0; r0 < RK; r0 += 11) {
            int nr = (RK - r0 < 11) ? (RK - r0) : 11;
            k1_chunk<<<NP / 256, 256, 0, stream>>>(x, Ucin, T, r0, nr);
            k2_chunk<<<dim3(7, 7, nr), 256, 0, stream>>>(Ukh, Ukw, Ukd, T, r0);
        }
        k3_out<<<NP / 256, 256, 0, stream>>>(T, Ucout, bias);
    }
}

// Round 13
// 143.533 us; speedup vs baseline: 1.4137x; 1.4137x over previous
//
#include <hip/hip_runtime.h>

// CP-decomposed 3D conv (AirConv3D): B=1, Cin=32, Cout=64, 56^3, K=3, pad=1, rank=53.
// All-f32. FINAL k3 VERDICT (R13-R20): simple two-phase k3c @ 4 blocks/CU = 43us
// beats every pipelined variant (54/61/98/105us) — barrier'd in-block pipelines
// lose to cross-block TLP overlap on this workload. k3c reverted verbatim.
// k1d VERDICT: grid-starved (R16: occ 29.8% = 784x4 waves grid limit), NOT
// compute-bound (VALU ~6-9us). R19 batched-shfl blew VGPR (~85 > 64 cliff).
// R21 k1d: 9-way rank split (batches of 6: r0=6*y, last=5) -> 28224 waves
// (3.4 rounds); batched dots->shfls->blend (12 indep DS ops back-to-back);
// VGPR budget 32 xv + 18 batch + ~10 = ~60 <= 64 via __launch_bounds__(256,8).
// Go/no-go: VGPR 56-64, k1d 15-22us, occ >= 60%.
// NOTE: one ~43us fillBuffer (268MB ws re-poison) sits in the timed window.
// Pipeline: k0_t -> k1d -> k3c. Fallback (small ws): R5 pipeline (known good).

#define NP 175616   // 56*56*56
#define NP2 87808   // NP/2 float2 columns
#define HSTR 3136   // 56*56
#define H2 1568     // HSTR/2 float2 per h-plane
#define W2 28       // 56/2 float2 per w-row
#define CIN 32
#define RK 53
#define RC0 27      // k3c chunk 0 ranks [0,27)
#define COUT 64
#define SCR 53      // fallback scratch slice base in d_out

// ---- k0: Ut[r*32+c] = Ucin[c*53+r] ----
__global__ __launch_bounds__(256) void k0_t(const float* __restrict__ Ucin,
                                            float* __restrict__ Ut)
{
    int t = blockIdx.x * 256 + threadIdx.x;
    if (t < RK * CIN) {
        int r = t >> 5, c = t & 31;
        Ut[t] = Ucin[c * RK + r];
    }
}

// ---- k1d: T1d[r,p] = d-conv(sum_c x[c,p]*Ut[r][c]), batched, 9-way split ----
// Block = 4 waves; wave = one (h,w) row (lanes 0..55 = d).
// blockIdx.y in [0,9): ranks [6y, min(6y+6,53)).
__global__ __launch_bounds__(256, 8) void k1d(
    const float* __restrict__ x, const float* __restrict__ Ut,
    const float* __restrict__ Ukd, float* __restrict__ T1d)
{
    const int lane = threadIdx.x & 63;          // d index
    const int row  = blockIdx.x * 4 + (threadIdx.x >> 6);   // (h,w) row in [0,3136)
    const int p    = row * 56 + lane;
    const bool act = (lane < 56);
    const int pc   = act ? p : (p - 8);         // clamp: lanes 56..63 in-bounds

    float xv[CIN];
#pragma unroll
    for (int c = 0; c < CIN; ++c) xv[c] = x[c * NP + pc];
#pragma unroll
    for (int c = 0; c < CIN; ++c) asm volatile("" : "+v"(xv[c]));  // pin in VGPRs

    const int r0 = blockIdx.y * 6;              // 0,6,...,48
    const int nr = (r0 + 6 <= RK) ? 6 : (RK - r0);   // 6 or 5 (last batch)

    // phase A: up to 6 dots (independent 4-partial chains)
    float acc[6];
#pragma unroll
    for (int rr = 0; rr < 6; ++rr) {
        if (rr < nr) {
            const float* U = Ut + (r0 + rr) * CIN;   // uniform -> s_load
            float a0 = 0.f, a1 = 0.f, a2 = 0.f, a3 = 0.f;
#pragma unroll
            for (int c = 0; c < CIN; c += 4) {
                a0 += xv[c]     * U[c];
                a1 += xv[c + 1] * U[c + 1];
                a2 += xv[c + 2] * U[c + 2];
                a3 += xv[c + 3] * U[c + 3];
            }
            acc[rr] = (a0 + a1) + (a2 + a3);
        }
    }

    // phase B: all shfls back-to-back (independent -> DS pipelines)
    float lm[6], rp[6];
#pragma unroll
    for (int rr = 0; rr < 6; ++rr) {
        if (rr < nr) {
            lm[rr] = __shfl_up(acc[rr], 1, 64);
            rp[rr] = __shfl_down(acc[rr], 1, 64);
        }
    }

    // phase C: blend + store
#pragma unroll
    for (int rr = 0; rr < 6; ++rr) {
        if (rr < nr) {
            const int r = r0 + rr;
            float l  = (lane == 0)  ? 0.f : lm[rr];
            float rv = (lane == 55) ? 0.f : rp[rr];
            float res = l * Ukd[r] + acc[rr] * Ukd[RK + r] + rv * Ukd[2 * RK + r];
            if (act) T1d[(size_t)r * NP + p] = res;
        }
    }
}

// ---- k3c: two-phase chunked w+h conv + 53->64 projection + bias (R16, 43us) ----
__global__ __launch_bounds__(512, 4) void k3c(
    const float2* __restrict__ Ta, const float* __restrict__ Ucout,
    const float* __restrict__ bias, const float* __restrict__ Ukh,
    const float* __restrict__ Ukw, float2* __restrict__ Out)
{
    __shared__ float2 tld[RC0][64];              // 13824 B

    const int lane = threadIdx.x & 63;
    const int wv   = threadIdx.x >> 6;           // 0..7

    // bijective XCD swizzle (m204); nwg = 1372
    const int nwg = gridDim.x;
    const int qx = nwg >> 3, rx = nwg & 7;
    const int xcd = blockIdx.x & 7, loc = blockIdx.x >> 3;
    const int swz = ((xcd < rx) ? xcd * (qx + 1) : rx * (qx + 1) + (xcd - rx) * qx) + loc;

    const int q  = swz * 64 + lane;              // float2 column in [0,NP2)
    const int h  = q / H2;
    const int rm = q - h * H2;
    const int w  = rm / W2;
    const int om = (h > 0)  ? -H2 : 0;
    const int op = (h < 55) ?  H2 : 0;
    const int oa = (w > 0)  ? -W2 : 0;
    const int oc = (w < 55) ?  W2 : 0;
    const float mh0 = (h > 0)  ? 1.f : 0.f;
    const float mh2 = (h < 55) ? 1.f : 0.f;
    const float mw0 = (w > 0)  ? 1.f : 0.f;
    const float mw2 = (w < 55) ? 1.f : 0.f;

    const float2* Sq = Ta + q;
    const int og = __builtin_amdgcn_readfirstlane(wv << 3);  // 0,8,...,56

    float2 a[8];

    // ================= chunk 0: ranks [0,27) =================
#pragma unroll 1
    for (int r = wv; r < RC0; r += 8) {
        const float2* S = Sq + (size_t)r * NP2;
        const float kw0 = mw0 * Ukw[r];
        const float kw1 = Ukw[RK + r];
        const float kw2 = mw2 * Ukw[2 * RK + r];
        const float kh0 = mh0 * Ukh[r];
        const float kh1 = Ukh[RK + r];
        const float kh2 = mh2 * Ukh[2 * RK + r];
        float2 v00 = S[om + oa], v01 = S[om], v02 = S[om + oc];
        float2 v10 = S[oa],      v11 = S[0],  v12 = S[oc];
        float2 v20 = S[op + oa], v21 = S[op], v22 = S[op + oc];
        float2 t;
        t.x = (v00.x * kw0 + v01.x * kw1 + v02.x * kw2) * kh0
            + (v10.x * kw0 + v11.x * kw1 + v12.x * kw2) * kh1
            + (v20.x * kw0 + v21.x * kw1 + v22.x * kw2) * kh2;
        t.y = (v00.y * kw0 + v01.y * kw1 + v02.y * kw2) * kh0
            + (v10.y * kw0 + v11.y * kw1 + v12.y * kw2) * kh1
            + (v20.y * kw0 + v21.y * kw1 + v22.y * kw2) * kh2;
        tld[r][lane] = t;
    }
    __syncthreads();

#pragma unroll
    for (int o = 0; o < 8; ++o) {
        float b = bias[og + o];
        a[o].x = b; a[o].y = b;
    }
#pragma unroll 4
    for (int r = 0; r < RC0; ++r) {
        float2 t = tld[r][lane];
        const float* Ur = Ucout + r * COUT + og;         // uniform -> s_load
#pragma unroll
        for (int o = 0; o < 8; ++o) {
            float u = Ur[o];
            a[o].x += t.x * u; a[o].y += t.y * u;
        }
    }
    __syncthreads();                                     // protect LDS overwrite

    // ================= chunk 1: ranks [27,53) =================
#pragma unroll 1
    for (int r = RC0 + wv; r < RK; r += 8) {
        const float2* S = Sq + (size_t)r * NP2;
        const float kw0 = mw0 * Ukw[r];
        const float kw1 = Ukw[RK + r];
        const float kw2 = mw2 * Ukw[2 * RK + r];
        const float kh0 = mh0 * Ukh[r];
        const float kh1 = Ukh[RK + r];
        const float kh2 = mh2 * Ukh[2 * RK + r];
        float2 v00 = S[om + oa], v01 = S[om], v02 = S[om + oc];
        float2 v10 = S[oa],      v11 = S[0],  v12 = S[oc];
        float2 v20 = S[op + oa], v21 = S[op], v22 = S[op + oc];
        float2 t;
        t.x = (v00.x * kw0 + v01.x * kw1 + v02.x * kw2) * kh0
            + (v10.x * kw0 + v11.x * kw1 + v12.x * kw2) * kh1
            + (v20.x * kw0 + v21.x * kw1 + v22.x * kw2) * kh2;
        t.y = (v00.y * kw0 + v01.y * kw1 + v02.y * kw2) * kh0
            + (v10.y * kw0 + v11.y * kw1 + v12.y * kw2) * kh1
            + (v20.y * kw0 + v21.y * kw1 + v22.y * kw2) * kh2;
        tld[r - RC0][lane] = t;
    }
    __syncthreads();

#pragma unroll 4
    for (int r = RC0; r < RK; ++r) {
        float2 t = tld[r - RC0][lane];
        const float* Ur = Ucout + r * COUT + og;
#pragma unroll
        for (int o = 0; o < 8; ++o) {
            float u = Ur[o];
            a[o].x += t.x * u; a[o].y += t.y * u;
        }
    }

#pragma unroll
    for (int o = 0; o < 8; ++o)
        Out[(size_t)(og + o) * NP2 + q] = a[o];
}

// ===================== fallback path (R5, known good) =====================

__global__ __launch_bounds__(256) void k1_chunk(
    const float* __restrict__ x, const float* __restrict__ Ucin,
    float* T, int r0, int nr)
{
    __shared__ float sU[11 * CIN];
    const int tid = threadIdx.x;
    for (int t = tid; t < nr * CIN; t += 256) {
        int lr = t >> 5, c = t & 31;
        sU[t] = Ucin[c * RK + (r0 + lr)];
    }
    __syncthreads();
    const int p = blockIdx.x * 256 + tid;
    float xv[CIN];
#pragma unroll
    for (int c = 0; c < CIN; ++c) xv[c] = x[c * NP + p];
#pragma unroll 1
    for (int lr = 0; lr < nr; ++lr) {
        float acc = 0.f;
#pragma unroll
        for (int c = 0; c < CIN; ++c) acc += xv[c] * sU[lr * CIN + c];
        T[(size_t)(SCR + lr) * NP + p] = acc;
    }
}

__global__ __launch_bounds__(256) void k2_chunk(
    const float* __restrict__ Ukh, const float* __restrict__ Ukw,
    const float* __restrict__ Ukd, float* T, int r0)
{
    __shared__ float sIn[5800];
    __shared__ float sA[5600];
    const int lr = blockIdx.z;
    const int r  = r0 + lr;
    const int h0 = blockIdx.x * 8, w0 = blockIdx.y * 8;
    const int tid = threadIdx.x;
    const float kh0 = Ukh[r], kh1 = Ukh[RK + r], kh2 = Ukh[2 * RK + r];
    const float kw0 = Ukw[r], kw1 = Ukw[RK + r], kw2 = Ukw[2 * RK + r];
    const float kd0 = Ukd[r], kd1 = Ukd[RK + r], kd2 = Ukd[2 * RK + r];
    const float* T1r = T + (size_t)(SCR + lr) * NP;

    for (int idx = tid; idx < 5800; idx += 256) {
        int d = idx % 58; int t2 = idx / 58; int ww = t2 % 10; int hh = t2 / 10;
        int gh = h0 + hh - 1, gw = w0 + ww - 1, gd = d - 1;
        float v = 0.f;
        if ((unsigned)gh < 56u && (unsigned)gw < 56u && (unsigned)gd < 56u)
            v = T1r[gh * HSTR + gw * 56 + gd];
        sIn[idx] = v;
    }
    __syncthreads();
    for (int idx = tid; idx < 5600; idx += 256) {
        int d = idx % 56; int t2 = idx / 56; int ww = t2 % 10; int hh = t2 / 10;
        const float* b = &sIn[(hh * 10 + ww) * 58 + d];
        sA[idx] = b[0] * kd0 + b[1] * kd1 + b[2] * kd2;
    }
    __syncthreads();
    const float k00 = kh0 * kw0, k01 = kh0 * kw1, k02 = kh0 * kw2;
    const float k10 = kh1 * kw0, k11 = kh1 * kw1, k12 = kh1 * kw2;
    const float k20 = kh2 * kw0, k21 = kh2 * kw1, k22 = kh2 * kw2;
    for (int idx = tid; idx < 3584; idx += 256) {
        int d = idx % 56; int t2 = idx / 56; int ww = t2 % 8; int hh = t2 / 8;
        const float* a = &sA[(hh * 10 + ww) * 56 + d];
        float acc = a[0]    * k00 + a[56]   * k01 + a[112]  * k02
                  + a[560]  * k10 + a[616]  * k11 + a[672]  * k12
                  + a[1120] * k20 + a[1176] * k21 + a[1232] * k22;
        T[(size_t)r * NP + (h0 + hh) * HSTR + (w0 + ww) * 56 + d] = acc;
    }
}

__global__ __launch_bounds__(256) void k3_out(
    float* T, const float* __restrict__ Ucout, const float* __restrict__ bias)
{
    __shared__ float sUo[RK * COUT];
    __shared__ float sB[COUT];
    const int tid = threadIdx.x;
    for (int t = tid; t < RK * COUT; t += 256) sUo[t] = Ucout[t];
    if (tid < COUT) sB[tid] = bias[tid];
    __syncthreads();
    const int p = blockIdx.x * 256 + tid;
    float acc[COUT];
#pragma unroll
    for (int o = 0; o < COUT; ++o) acc[o] = sB[o];
#pragma unroll 1
    for (int r = 0; r < RK; ++r) {
        float t = T[(size_t)r * NP + p];
        const float* Ur = &sUo[r * COUT];
#pragma unroll
        for (int o = 0; o < COUT; ++o) acc[o] += t * Ur[o];
    }
#pragma unroll
    for (int o = 0; o < COUT; ++o) T[(size_t)o * NP + p] = acc[o];
}

// ===================== launch =====================

extern "C" void kernel_launch(void* const* d_in, const int* in_sizes, int n_in,
                              void* d_out, int out_size, void* d_ws, size_t ws_size,
                              hipStream_t stream)
{
    const float* x     = (const float*)d_in[0];
    const float* Ukh   = (const float*)d_in[1];
    const float* Ukw   = (const float*)d_in[2];
    const float* Ukd   = (const float*)d_in[3];
    const float* Ucin  = (const float*)d_in[4];
    const float* Ucout = (const float*)d_in[5];
    const float* bias  = (const float*)d_in[6];

    const size_t t1_bytes = (size_t)RK * NP * sizeof(float);   // 37.2 MB

    if (ws_size >= t1_bytes + 8192) {
        float* T1 = (float*)d_ws;
        float* Ut = (float*)((char*)d_ws + t1_bytes);          // 6.8 KB
        k0_t<<<7, 256, 0, stream>>>(Ucin, Ut);
        k1d<<<dim3(HSTR / 4, 9), 256, 0, stream>>>(x, Ut, Ukd, T1);  // 7056 blocks
        k3c<<<NP2 / 64, 512, 0, stream>>>((const float2*)T1, Ucout, bias, Ukh,
                                          Ukw, (float2*)d_out);      // 1372 blocks
    } else {
        float* T = (float*)d_out;
        for (int r0 = 0; r0 < RK; r0 += 11) {
            int nr = (RK - r0 < 11) ? (RK - r0) : 11;
            k1_chunk<<<NP / 256, 256, 0, stream>>>(x, Ucin, T, r0, nr);
            k2_chunk<<<dim3(7, 7, nr), 256, 0, stream>>>(Ukh, Ukw, Ukd, T, r0);
        }
        k3_out<<<NP / 256, 256, 0, stream>>>(T, Ucout, bias);
    }
}